// Round 17
// baseline (121.946 us; speedup 1.0000x reference)
//
#include <hip/hip_runtime.h>
#include <hip/hip_bf16.h>
#include <stdint.h>

// MHA: B=2, S=2048, D=1024, H=16, dk=64.  All GEMM-shaped work in bf16 MFMA.
// k_prep (all conversions, one launch) | QKV gemm 8 waves/block (512 thd,
// 128x128 tile, wave-tile 64x32 -> ~24 waves/CU vs 12; LOG2E/8 in Wq,bq; V
// transposed [bh][d][s]) | flash attn r13 verbatim: 16x16 MFMA, QBLK=128,
// 2 q-frags/wave serial f-phases, no-max softmax P=exp2(S) RNE-packed,
// l via ones-row MFMA, KVBLK=64 fragment-order global_load_lds dbuf,
// in-kernel 1/l normalize | O-proj gemm 8 waves/block -> f32.

#define LOG2E 1.4426950408889634f

typedef float f32x4 __attribute__((ext_vector_type(4)));
typedef short bf16x8 __attribute__((ext_vector_type(8)));
typedef short bf16x4 __attribute__((ext_vector_type(4)));

__device__ __forceinline__ unsigned short f2bf(float f) {
  __hip_bfloat16 h = __float2bfloat16(f);   // hw v_cvt, RNE
  return reinterpret_cast<unsigned short&>(h);
}

#define GLDS(g, l) __builtin_amdgcn_global_load_lds(                          \
    (const __attribute__((address_space(1))) void*)(g),                       \
    (__attribute__((address_space(3))) void*)(l), 16, 0, 0)

// ---------- all prep conversions in ONE kernel ----------
__global__ __launch_bounds__(256) void k_prep(const float* __restrict__ x,
                                              const float* __restrict__ wq,
                                              const float* __restrict__ wk,
                                              const float* __restrict__ wv,
                                              const float* __restrict__ wo,
                                              const float* __restrict__ bq,
                                              const float* __restrict__ bk,
                                              const float* __restrict__ bv,
                                              unsigned short* __restrict__ xb,
                                              unsigned short* __restrict__ Wb,
                                              unsigned short* __restrict__ Wob,
                                              float* __restrict__ biasQ) {
  const int blk = blockIdx.x;
  if (blk >= 8192) {
    int i = (blk - 8192) * 256 + threadIdx.x;
    float v;
    if (i < 1024) v = bq[i] * (0.125f * LOG2E);
    else if (i < 2048) v = bk[i - 1024];
    else v = bv[i - 2048];
    biasQ[i] = v;
    return;
  }
  const int gi = blk * 256 + threadIdx.x;
  const float* src;
  unsigned short* dst;
  float scale = 1.0f;
  int off;
  if (gi < 1048576) { src = x; dst = xb; off = gi; }
  else {
    const int wi = gi - 1048576;
    const int m = wi >> 18;
    off = wi & 262143;
    src = (m == 0) ? wq : (m == 1) ? wk : (m == 2) ? wv : wo;
    dst = (m == 3) ? Wob : (Wb + m * 1048576);
    if (m == 0) scale = 0.125f * LOG2E;
  }
  float4 v = ((const float4*)src)[off];
  ushort4 o;
  o.x = f2bf(v.x * scale);
  o.y = f2bf(v.y * scale);
  o.z = f2bf(v.z * scale);
  o.w = f2bf(v.w * scale);
  ((ushort4*)dst)[off] = o;
}

// ---------- QKV GEMM, 8 waves/block: C[m][n] = sum_k A[m][k]*B[n][k]+b[n] --
// 512 threads; wave wid: wr = wid>>2 (row half), wc = wid&3 (col quarter).
// Wave tile 64x32 = acc[4][2].  One GLDS per matrix per k-step (512x16B=8KB).
__global__ __launch_bounds__(512) void k_gemm0(const unsigned short* __restrict__ A,
                                               const unsigned short* __restrict__ B,
                                               const float* __restrict__ bias,
                                               unsigned short* __restrict__ outp) {
  __shared__ unsigned short As[128 * 32];
  __shared__ unsigned short Bs[128 * 32];
  const int tid = threadIdx.x;
  const int lane = tid & 63, wid = tid >> 6;
  const int wr = wid >> 2, wc = wid & 3;
  const int r = lane & 15, g = lane >> 4;
  const int bm = blockIdx.x, bn = blockIdx.y;

  const unsigned short* gA = A + (size_t)bm * 128 * 1024;
  const unsigned short* gB = B + (size_t)bn * 128 * 1024;
  const int row0 = tid >> 2, cg = (tid & 3) * 8;   // row0 in [0,128)

  f32x4 acc[4][2] = {};

  for (int k0 = 0; k0 < 1024; k0 += 32) {
    __syncthreads();
    GLDS(gA + (size_t)row0 * 1024 + k0 + cg, As + row0 * 32 + cg);
    GLDS(gB + (size_t)row0 * 1024 + k0 + cg, Bs + row0 * 32 + cg);
    __syncthreads();

    bf16x8 af[4], bfr[2];
#pragma unroll
    for (int i = 0; i < 4; i++)
      af[i] = *(const bf16x8*)(As + (wr * 64 + i * 16 + r) * 32 + g * 8);
#pragma unroll
    for (int j = 0; j < 2; j++)
      bfr[j] = *(const bf16x8*)(Bs + (wc * 32 + j * 16 + r) * 32 + g * 8);
#pragma unroll
    for (int i = 0; i < 4; i++)
#pragma unroll
      for (int j = 0; j < 2; j++)
        acc[i][j] = __builtin_amdgcn_mfma_f32_16x16x32_bf16(af[i], bfr[j], acc[i][j], 0, 0, 0);
  }

#pragma unroll
  for (int i = 0; i < 4; i++) {
    const int rowb = bm * 128 + wr * 64 + i * 16 + g * 4;
#pragma unroll
    for (int j = 0; j < 2; j++) {
      const int col = bn * 128 + wc * 32 + j * 16 + r;
      const float bv = bias[col];
      const int mat = col >> 10, nn = col & 1023;
      const int hh = nn >> 6, dd = nn & 63;
      const int bb = rowb >> 11, ss = rowb & 2047;
      if (mat == 2) {
        // V transposed [bh][d][s]: 4 t-values s-consecutive -> one 8B store
        bf16x4 ov;
#pragma unroll
        for (int t = 0; t < 4; t++) ov[t] = (short)f2bf(acc[i][j][t] + bv);
        *(bf16x4*)(&outp[(size_t)2 * 4194304 +
            (size_t)((bb * 16 + hh) * 64 + dd) * 2048 + ss]) = ov;
      } else {
#pragma unroll
        for (int t = 0; t < 4; t++)
          outp[(size_t)mat * 4194304 +
               (size_t)((bb * 16 + hh) * 2048 + ss + t) * 64 + dd] =
              f2bf(acc[i][j][t] + bv);
      }
    }
  }
}

// ---------- O-proj GEMM: out = mrg @ Wo^T + bo (f32), 8 waves/block ----------
__global__ __launch_bounds__(512) void k_gemm1(const unsigned short* __restrict__ A,
                                               const unsigned short* __restrict__ B,
                                               const float* __restrict__ bias,
                                               float* __restrict__ outp) {
  __shared__ unsigned short As[128 * 32];
  __shared__ unsigned short Bs[128 * 32];
  const int tid = threadIdx.x;
  const int lane = tid & 63, wid = tid >> 6;
  const int wr = wid >> 2, wc = wid & 3;
  const int r = lane & 15, g = lane >> 4;
  const int bm = blockIdx.x, bn = blockIdx.y;

  const unsigned short* gA = A + (size_t)bm * 128 * 1024;
  const unsigned short* gB = B + (size_t)bn * 128 * 1024;
  const int row0 = tid >> 2, cg = (tid & 3) * 8;   // row0 in [0,128)

  f32x4 acc[4][2] = {};

  for (int k0 = 0; k0 < 1024; k0 += 32) {
    __syncthreads();
    GLDS(gA + (size_t)row0 * 1024 + k0 + cg, As + row0 * 32 + cg);
    GLDS(gB + (size_t)row0 * 1024 + k0 + cg, Bs + row0 * 32 + cg);
    __syncthreads();

    bf16x8 af[4], bfr[2];
#pragma unroll
    for (int i = 0; i < 4; i++)
      af[i] = *(const bf16x8*)(As + (wr * 64 + i * 16 + r) * 32 + g * 8);
#pragma unroll
    for (int j = 0; j < 2; j++)
      bfr[j] = *(const bf16x8*)(Bs + (wc * 32 + j * 16 + r) * 32 + g * 8);
#pragma unroll
    for (int i = 0; i < 4; i++)
#pragma unroll
      for (int j = 0; j < 2; j++)
        acc[i][j] = __builtin_amdgcn_mfma_f32_16x16x32_bf16(af[i], bfr[j], acc[i][j], 0, 0, 0);
  }

#pragma unroll
  for (int i = 0; i < 4; i++) {
    const int rowb = bm * 128 + wr * 64 + i * 16 + g * 4;
#pragma unroll
    for (int j = 0; j < 2; j++) {
      const int col = bn * 128 + wc * 32 + j * 16 + r;
      const float bv = bias[col];
#pragma unroll
      for (int t = 0; t < 4; t++)
        outp[(size_t)(rowb + t) * 1024 + col] = acc[i][j][t] + bv;
    }
  }
}

// ---------- flash attention (r13 structure verbatim) ----------
__global__ __launch_bounds__(256) void k_attn(const unsigned short* __restrict__ Q,
                                              const unsigned short* __restrict__ Km,
                                              const unsigned short* __restrict__ Vt,
                                              unsigned short* __restrict__ merged) {
  __shared__ unsigned short Kb[2][4096];
  __shared__ unsigned short Vb[2][4096];
  __shared__ unsigned short Pl[4][1024];
  const int tid = threadIdx.x;
  const int lane = tid & 63, w = tid >> 6;
  const int r = lane & 15, g = lane >> 4;
  const int bh = blockIdx.y;
  const int b = bh >> 4, h = bh & 15;
  const int q0 = blockIdx.x * 128;

  const unsigned short* Qh  = Q  + (size_t)bh * 131072;   // [s][d]
  const unsigned short* Kh  = Km + (size_t)bh * 131072;   // [s][d]
  const unsigned short* Vth = Vt + (size_t)bh * 131072;   // [d][s]

  const int qrowA = q0 + w * 32 + r;
  bf16x8 bQ[2][2];
#pragma unroll
  for (int f = 0; f < 2; f++) {
    bQ[f][0] = *(const bf16x8*)(Qh + (size_t)(qrowA + f * 16) * 64 + g * 8);
    bQ[f][1] = *(const bf16x8*)(Qh + (size_t)(qrowA + f * 16) * 64 + 32 + g * 8);
  }

  int ksrc[2], vsrc[2];
#pragma unroll
  for (int op = 0; op < 2; op++) {
    const int c = op * 256 + tid;
    const int st = c >> 7, dh = (c >> 6) & 1, gg = (c >> 4) & 3, rr = c & 15;
    ksrc[op] = (st * 16 + rr) * 64 + dh * 32 + gg * 8;
    vsrc[op] = (st * 16 + rr) * 2048 + dh * 32 + gg * 8;
  }
  const int ldst = tid * 8;

  GLDS(Kh + ksrc[0],  &Kb[0][ldst]);
  GLDS(Kh + ksrc[1],  &Kb[0][2048 + ldst]);
  GLDS(Vth + vsrc[0], &Vb[0][ldst]);
  GLDS(Vth + vsrc[1], &Vb[0][2048 + ldst]);
  __syncthreads();

  f32x4 o[2][4] = {};
  f32x4 ol[2] = {};
  bf16x8 aONE;
#pragma unroll
  for (int j = 0; j < 8; j++) aONE[j] = (short)0x3F80;   // bf16 1.0

  const unsigned swz = ((unsigned)(r & 7)) << 4;
  char* const plw = (char*)&Pl[w][0];

  for (int t = 0; t < 32; ++t) {
    const int cur = t & 1;
    if (t < 31) {
      const size_t kv = (size_t)(t + 1) * 64;
      GLDS(Kh + kv * 64 + ksrc[0],  &Kb[cur ^ 1][ldst]);
      GLDS(Kh + kv * 64 + ksrc[1],  &Kb[cur ^ 1][2048 + ldst]);
      GLDS(Vth + kv + vsrc[0], &Vb[cur ^ 1][ldst]);
      GLDS(Vth + kv + vsrc[1], &Vb[cur ^ 1][2048 + ldst]);
    }

    const unsigned short* kb = &Kb[cur][lane * 8];
    const unsigned short* vb = &Vb[cur][lane * 8];

    // K and V fragments once -> registers (shared by both q-frags)
    bf16x8 kf[4][2], vf[4][2];
#pragma unroll
    for (int st = 0; st < 4; st++) {
      kf[st][0] = *(const bf16x8*)(kb + st * 1024);
      kf[st][1] = *(const bf16x8*)(kb + st * 1024 + 512);
      vf[st][0] = *(const bf16x8*)(vb + st * 1024);
      vf[st][1] = *(const bf16x8*)(vb + st * 1024 + 512);
    }

#pragma unroll
    for (int f = 0; f < 2; f++) {
      // S^T (log2 units)
      f32x4 St[4];
#pragma unroll
      for (int st = 0; st < 4; st++) {
        f32x4 z = {0.f, 0.f, 0.f, 0.f};
        z = __builtin_amdgcn_mfma_f32_16x16x32_bf16(kf[st][0], bQ[f][0], z, 0, 0, 0);
        St[st] = __builtin_amdgcn_mfma_f32_16x16x32_bf16(kf[st][1], bQ[f][1], z, 0, 0, 0);
      }

      // P = exp2(S) raw; RNE pack to bf16; per-wave LDS roundtrip (swizzled)
#pragma unroll
      for (int st = 0; st < 4; st++) {
        bf16x4 pk;
#pragma unroll
        for (int u = 0; u < 4; u++)
          pk[u] = (short)f2bf(__builtin_amdgcn_exp2f(St[st][u]));
        *(bf16x4*)(plw + (((unsigned)(r * 128 + st * 32 + g * 8)) ^ swz)) = pk;
      }
      const bf16x8 pb0 = *(const bf16x8*)(plw + (((unsigned)(r * 128 + g * 16)) ^ swz));
      const bf16x8 pb1 = *(const bf16x8*)(plw + (((unsigned)(r * 128 + 64 + g * 16)) ^ swz));

      // PV + l (ones-row MFMA)
#pragma unroll
      for (int c4 = 0; c4 < 4; c4++) {
        o[f][c4] = __builtin_amdgcn_mfma_f32_16x16x32_bf16(vf[c4][0], pb0, o[f][c4], 0, 0, 0);
        o[f][c4] = __builtin_amdgcn_mfma_f32_16x16x32_bf16(vf[c4][1], pb1, o[f][c4], 0, 0, 0);
      }
      ol[f] = __builtin_amdgcn_mfma_f32_16x16x32_bf16(aONE, pb0, ol[f], 0, 0, 0);
      ol[f] = __builtin_amdgcn_mfma_f32_16x16x32_bf16(aONE, pb1, ol[f], 0, 0, 0);
    }

    __syncthreads();
  }

  // epilogue: lane holds attn^T[d=c4*16+g*4+u][q]; l(q) = ol[f][0]
#pragma unroll
  for (int f = 0; f < 2; f++) {
    const float inv = 1.0f / ol[f][0];
    const size_t base = (size_t)(b * 2048 + qrowA + f * 16) * 1024 + h * 64;
#pragma unroll
    for (int c4 = 0; c4 < 4; c4++) {
      bf16x4 ov;
#pragma unroll
      for (int u = 0; u < 4; u++) ov[u] = (short)f2bf(o[f][c4][u] * inv);
      *(bf16x4*)(&merged[base + c4 * 16 + g * 4]) = ov;
    }
  }
}

extern "C" void kernel_launch(void* const* d_in, const int* in_sizes, int n_in,
                              void* d_out, int out_size, void* d_ws, size_t ws_size,
                              hipStream_t stream) {
  const float* x  = (const float*)d_in[0];
  const float* Wq = (const float*)d_in[1];
  const float* bq = (const float*)d_in[2];
  const float* Wk = (const float*)d_in[3];
  const float* bk = (const float*)d_in[4];
  const float* Wv = (const float*)d_in[5];
  const float* bv = (const float*)d_in[6];
  const float* Wo = (const float*)d_in[7];
  const float* bo = (const float*)d_in[8];

  if (ws_size < (size_t)42479616) return;

  unsigned short* ws  = (unsigned short*)d_ws;
  unsigned short* qkv  = ws;                       // Q|K [32][2048][64]; Vt [32][64][2048]
  unsigned short* Wob  = ws + 12582912;            // Wo bf16 [1024][1024]
  float* biasQ = (float*)(ws + 13631488);          // fused qkv bias [3072]
  unsigned short* xb = ws + 13899776;              // x bf16 [4096][1024] (dead after gemm0)
  unsigned short* Wb = ws + 18094080;              // Wq'|Wk|Wv bf16 (dead after gemm0)
  unsigned short* mrg = ws + 13899776;             // merged bf16 (overlays dead xb)

  k_prep<<<dim3(8204), dim3(256), 0, stream>>>(x, Wq, Wk, Wv, Wo, bq, bk, bv,
                                               xb, Wb, Wob, biasQ);
  k_gemm0<<<dim3(32, 24), dim3(512), 0, stream>>>(xb, Wb, biasQ, qkv);
  k_attn<<<dim3(16, 32), dim3(256), 0, stream>>>(
      qkv, qkv + 4194304, qkv + 8388608, mrg);
  k_gemm1<<<dim3(32, 8), dim3(512), 0, stream>>>(mrg, Wob, bo, (float*)d_out);
}

// Round 18
// 118.706 us; speedup vs baseline: 1.0273x; 1.0273x over previous
//
#include <hip/hip_runtime.h>
#include <hip/hip_bf16.h>
#include <stdint.h>

// MHA: B=2, S=2048, D=1024, H=16, dk=64.  All GEMM-shaped work in bf16 MFMA.
// r16 composition (measured best 120.4us) + T1 XCD-aware block swizzle on
// attn: all 16 q-blocks of a given bh land on ONE XCD (bh = 4*(bid&7) + ...)
// so each XCD's L2 holds only 4 heads' K/V (2MB, L2-resident) instead of
// thrashing through all 32.  gemm0 reverted to 4-wave r16 form (8-wave
// regressed in r17).

#define LOG2E 1.4426950408889634f

typedef float f32x4 __attribute__((ext_vector_type(4)));
typedef short bf16x8 __attribute__((ext_vector_type(8)));
typedef short bf16x4 __attribute__((ext_vector_type(4)));

__device__ __forceinline__ unsigned short f2bf(float f) {
  __hip_bfloat16 h = __float2bfloat16(f);   // hw v_cvt, RNE
  return reinterpret_cast<unsigned short&>(h);
}

#define GLDS(g, l) __builtin_amdgcn_global_load_lds(                          \
    (const __attribute__((address_space(1))) void*)(g),                       \
    (__attribute__((address_space(3))) void*)(l), 16, 0, 0)

// ---------- all prep conversions in ONE kernel ----------
__global__ __launch_bounds__(256) void k_prep(const float* __restrict__ x,
                                              const float* __restrict__ wq,
                                              const float* __restrict__ wk,
                                              const float* __restrict__ wv,
                                              const float* __restrict__ wo,
                                              const float* __restrict__ bq,
                                              const float* __restrict__ bk,
                                              const float* __restrict__ bv,
                                              unsigned short* __restrict__ xb,
                                              unsigned short* __restrict__ Wb,
                                              unsigned short* __restrict__ Wob,
                                              float* __restrict__ biasQ) {
  const int blk = blockIdx.x;
  if (blk >= 8192) {
    int i = (blk - 8192) * 256 + threadIdx.x;
    float v;
    if (i < 1024) v = bq[i] * (0.125f * LOG2E);
    else if (i < 2048) v = bk[i - 1024];
    else v = bv[i - 2048];
    biasQ[i] = v;
    return;
  }
  const int gi = blk * 256 + threadIdx.x;
  const float* src;
  unsigned short* dst;
  float scale = 1.0f;
  int off;
  if (gi < 1048576) { src = x; dst = xb; off = gi; }
  else {
    const int wi = gi - 1048576;
    const int m = wi >> 18;
    off = wi & 262143;
    src = (m == 0) ? wq : (m == 1) ? wk : (m == 2) ? wv : wo;
    dst = (m == 3) ? Wob : (Wb + m * 1048576);
    if (m == 0) scale = 0.125f * LOG2E;
  }
  float4 v = ((const float4*)src)[off];
  ushort4 o;
  o.x = f2bf(v.x * scale);
  o.y = f2bf(v.y * scale);
  o.z = f2bf(v.z * scale);
  o.w = f2bf(v.w * scale);
  ((ushort4*)dst)[off] = o;
}

// ---------- QKV GEMM (r16 4-wave form): C = A @ B^T + bias ----------
__global__ __launch_bounds__(256) void k_gemm0(const unsigned short* __restrict__ A,
                                               const unsigned short* __restrict__ B,
                                               const float* __restrict__ bias,
                                               unsigned short* __restrict__ outp) {
  __shared__ unsigned short As[128 * 32];
  __shared__ unsigned short Bs[128 * 32];
  const int tid = threadIdx.x;
  const int lane = tid & 63, wid = tid >> 6;
  const int wr = wid >> 1, wc = wid & 1;
  const int r = lane & 15, g = lane >> 4;
  const int bm = blockIdx.x, bn = blockIdx.y;

  const unsigned short* gA = A + (size_t)bm * 128 * 1024;
  const unsigned short* gB = B + (size_t)bn * 128 * 1024;
  const int row0 = tid >> 2, cg = (tid & 3) * 8;

  f32x4 acc[4][4] = {};

  for (int k0 = 0; k0 < 1024; k0 += 32) {
    __syncthreads();
    GLDS(gA + (size_t)row0 * 1024 + k0 + cg,        As + row0 * 32 + cg);
    GLDS(gA + (size_t)(row0 + 64) * 1024 + k0 + cg, As + (row0 + 64) * 32 + cg);
    GLDS(gB + (size_t)row0 * 1024 + k0 + cg,        Bs + row0 * 32 + cg);
    GLDS(gB + (size_t)(row0 + 64) * 1024 + k0 + cg, Bs + (row0 + 64) * 32 + cg);
    __syncthreads();

    bf16x8 af[4], bfr[4];
#pragma unroll
    for (int i = 0; i < 4; i++) {
      af[i]  = *(const bf16x8*)(As + (wr * 64 + i * 16 + r) * 32 + g * 8);
      bfr[i] = *(const bf16x8*)(Bs + (wc * 64 + i * 16 + r) * 32 + g * 8);
    }
#pragma unroll
    for (int i = 0; i < 4; i++)
#pragma unroll
      for (int j = 0; j < 4; j++)
        acc[i][j] = __builtin_amdgcn_mfma_f32_16x16x32_bf16(af[i], bfr[j], acc[i][j], 0, 0, 0);
  }

#pragma unroll
  for (int i = 0; i < 4; i++) {
    const int rowb = bm * 128 + wr * 64 + i * 16 + g * 4;
#pragma unroll
    for (int j = 0; j < 4; j++) {
      const int col = bn * 128 + wc * 64 + j * 16 + r;
      const float bv = bias[col];
      const int mat = col >> 10, nn = col & 1023;
      const int hh = nn >> 6, dd = nn & 63;
      const int bb = rowb >> 11, ss = rowb & 2047;
      if (mat == 2) {
        // V transposed [bh][d][s]: 4 t-values s-consecutive -> one 8B store
        bf16x4 ov;
#pragma unroll
        for (int t = 0; t < 4; t++) ov[t] = (short)f2bf(acc[i][j][t] + bv);
        *(bf16x4*)(&outp[(size_t)2 * 4194304 +
            (size_t)((bb * 16 + hh) * 64 + dd) * 2048 + ss]) = ov;
      } else {
#pragma unroll
        for (int t = 0; t < 4; t++)
          outp[(size_t)mat * 4194304 +
               (size_t)((bb * 16 + hh) * 2048 + ss + t) * 64 + dd] =
              f2bf(acc[i][j][t] + bv);
      }
    }
  }
}

// ---------- O-proj GEMM: out = mrg @ Wo^T + bo (f32), 8 waves/block ----------
__global__ __launch_bounds__(512) void k_gemm1(const unsigned short* __restrict__ A,
                                               const unsigned short* __restrict__ B,
                                               const float* __restrict__ bias,
                                               float* __restrict__ outp) {
  __shared__ unsigned short As[128 * 32];
  __shared__ unsigned short Bs[128 * 32];
  const int tid = threadIdx.x;
  const int lane = tid & 63, wid = tid >> 6;
  const int wr = wid >> 2, wc = wid & 3;
  const int r = lane & 15, g = lane >> 4;
  const int bm = blockIdx.x, bn = blockIdx.y;

  const unsigned short* gA = A + (size_t)bm * 128 * 1024;
  const unsigned short* gB = B + (size_t)bn * 128 * 1024;
  const int row0 = tid >> 2, cg = (tid & 3) * 8;   // row0 in [0,128)

  f32x4 acc[4][2] = {};

  for (int k0 = 0; k0 < 1024; k0 += 32) {
    __syncthreads();
    GLDS(gA + (size_t)row0 * 1024 + k0 + cg, As + row0 * 32 + cg);
    GLDS(gB + (size_t)row0 * 1024 + k0 + cg, Bs + row0 * 32 + cg);
    __syncthreads();

    bf16x8 af[4], bfr[2];
#pragma unroll
    for (int i = 0; i < 4; i++)
      af[i] = *(const bf16x8*)(As + (wr * 64 + i * 16 + r) * 32 + g * 8);
#pragma unroll
    for (int j = 0; j < 2; j++)
      bfr[j] = *(const bf16x8*)(Bs + (wc * 32 + j * 16 + r) * 32 + g * 8);
#pragma unroll
    for (int i = 0; i < 4; i++)
#pragma unroll
      for (int j = 0; j < 2; j++)
        acc[i][j] = __builtin_amdgcn_mfma_f32_16x16x32_bf16(af[i], bfr[j], acc[i][j], 0, 0, 0);
  }

#pragma unroll
  for (int i = 0; i < 4; i++) {
    const int rowb = bm * 128 + wr * 64 + i * 16 + g * 4;
#pragma unroll
    for (int j = 0; j < 2; j++) {
      const int col = bn * 128 + wc * 32 + j * 16 + r;
      const float bv = bias[col];
#pragma unroll
      for (int t = 0; t < 4; t++)
        outp[(size_t)(rowb + t) * 1024 + col] = acc[i][j][t] + bv;
    }
  }
}

// ---------- flash attention (r13 structure + XCD-aware block swizzle) ------
// grid 512 1-D blocks.  Swizzle: xcd = bid&7 owns bh in [4*xcd, 4*xcd+4);
// j = bid>>3: bh = 4*xcd + (j>>4), q-tile = j&15.  With round-robin dispatch
// (bid%8 -> XCD) each XCD's 64 blocks touch only 4 heads' K/V (2MB,
// L2-resident) instead of all 32 (16MB thrash).  Pure perf heuristic -
// any dispatch mapping is correct.
__global__ __launch_bounds__(256) void k_attn(const unsigned short* __restrict__ Q,
                                              const unsigned short* __restrict__ Km,
                                              const unsigned short* __restrict__ Vt,
                                              unsigned short* __restrict__ merged) {
  __shared__ unsigned short Kb[2][4096];
  __shared__ unsigned short Vb[2][4096];
  __shared__ unsigned short Pl[4][1024];
  const int tid = threadIdx.x;
  const int lane = tid & 63, w = tid >> 6;
  const int r = lane & 15, g = lane >> 4;
  const int bid = blockIdx.x;
  const int j = bid >> 3;
  const int bh = ((bid & 7) << 2) + (j >> 4);   // 4 heads per XCD partition
  const int b = bh >> 4, h = bh & 15;
  const int q0 = (j & 15) * 128;

  const unsigned short* Qh  = Q  + (size_t)bh * 131072;   // [s][d]
  const unsigned short* Kh  = Km + (size_t)bh * 131072;   // [s][d]
  const unsigned short* Vth = Vt + (size_t)bh * 131072;   // [d][s]

  const int qrowA = q0 + w * 32 + r;
  bf16x8 bQ[2][2];
#pragma unroll
  for (int f = 0; f < 2; f++) {
    bQ[f][0] = *(const bf16x8*)(Qh + (size_t)(qrowA + f * 16) * 64 + g * 8);
    bQ[f][1] = *(const bf16x8*)(Qh + (size_t)(qrowA + f * 16) * 64 + 32 + g * 8);
  }

  int ksrc[2], vsrc[2];
#pragma unroll
  for (int op = 0; op < 2; op++) {
    const int c = op * 256 + tid;
    const int st = c >> 7, dh = (c >> 6) & 1, gg = (c >> 4) & 3, rr = c & 15;
    ksrc[op] = (st * 16 + rr) * 64 + dh * 32 + gg * 8;
    vsrc[op] = (st * 16 + rr) * 2048 + dh * 32 + gg * 8;
  }
  const int ldst = tid * 8;

  GLDS(Kh + ksrc[0],  &Kb[0][ldst]);
  GLDS(Kh + ksrc[1],  &Kb[0][2048 + ldst]);
  GLDS(Vth + vsrc[0], &Vb[0][ldst]);
  GLDS(Vth + vsrc[1], &Vb[0][2048 + ldst]);
  __syncthreads();

  f32x4 o[2][4] = {};
  f32x4 ol[2] = {};
  bf16x8 aONE;
#pragma unroll
  for (int j2 = 0; j2 < 8; j2++) aONE[j2] = (short)0x3F80;   // bf16 1.0

  const unsigned swz = ((unsigned)(r & 7)) << 4;
  char* const plw = (char*)&Pl[w][0];

  for (int t = 0; t < 32; ++t) {
    const int cur = t & 1;
    if (t < 31) {
      const size_t kv = (size_t)(t + 1) * 64;
      GLDS(Kh + kv * 64 + ksrc[0],  &Kb[cur ^ 1][ldst]);
      GLDS(Kh + kv * 64 + ksrc[1],  &Kb[cur ^ 1][2048 + ldst]);
      GLDS(Vth + kv + vsrc[0], &Vb[cur ^ 1][ldst]);
      GLDS(Vth + kv + vsrc[1], &Vb[cur ^ 1][2048 + ldst]);
    }

    const unsigned short* kb = &Kb[cur][lane * 8];
    const unsigned short* vb = &Vb[cur][lane * 8];

    // K and V fragments once -> registers (shared by both q-frags)
    bf16x8 kf[4][2], vf[4][2];
#pragma unroll
    for (int st = 0; st < 4; st++) {
      kf[st][0] = *(const bf16x8*)(kb + st * 1024);
      kf[st][1] = *(const bf16x8*)(kb + st * 1024 + 512);
      vf[st][0] = *(const bf16x8*)(vb + st * 1024);
      vf[st][1] = *(const bf16x8*)(vb + st * 1024 + 512);
    }

#pragma unroll
    for (int f = 0; f < 2; f++) {
      // S^T (log2 units)
      f32x4 St[4];
#pragma unroll
      for (int st = 0; st < 4; st++) {
        f32x4 z = {0.f, 0.f, 0.f, 0.f};
        z = __builtin_amdgcn_mfma_f32_16x16x32_bf16(kf[st][0], bQ[f][0], z, 0, 0, 0);
        St[st] = __builtin_amdgcn_mfma_f32_16x16x32_bf16(kf[st][1], bQ[f][1], z, 0, 0, 0);
      }

      // P = exp2(S) raw; RNE pack to bf16; per-wave LDS roundtrip (swizzled)
#pragma unroll
      for (int st = 0; st < 4; st++) {
        bf16x4 pk;
#pragma unroll
        for (int u = 0; u < 4; u++)
          pk[u] = (short)f2bf(__builtin_amdgcn_exp2f(St[st][u]));
        *(bf16x4*)(plw + (((unsigned)(r * 128 + st * 32 + g * 8)) ^ swz)) = pk;
      }
      const bf16x8 pb0 = *(const bf16x8*)(plw + (((unsigned)(r * 128 + g * 16)) ^ swz));
      const bf16x8 pb1 = *(const bf16x8*)(plw + (((unsigned)(r * 128 + 64 + g * 16)) ^ swz));

      // PV + l (ones-row MFMA)
#pragma unroll
      for (int c4 = 0; c4 < 4; c4++) {
        o[f][c4] = __builtin_amdgcn_mfma_f32_16x16x32_bf16(vf[c4][0], pb0, o[f][c4], 0, 0, 0);
        o[f][c4] = __builtin_amdgcn_mfma_f32_16x16x32_bf16(vf[c4][1], pb1, o[f][c4], 0, 0, 0);
      }
      ol[f] = __builtin_amdgcn_mfma_f32_16x16x32_bf16(aONE, pb0, ol[f], 0, 0, 0);
      ol[f] = __builtin_amdgcn_mfma_f32_16x16x32_bf16(aONE, pb1, ol[f], 0, 0, 0);
    }

    __syncthreads();
  }

  // epilogue: lane holds attn^T[d=c4*16+g*4+u][q]; l(q) = ol[f][0]
#pragma unroll
  for (int f = 0; f < 2; f++) {
    const float inv = 1.0f / ol[f][0];
    const size_t base = (size_t)(b * 2048 + qrowA + f * 16) * 1024 + h * 64;
#pragma unroll
    for (int c4 = 0; c4 < 4; c4++) {
      bf16x4 ov;
#pragma unroll
      for (int u = 0; u < 4; u++) ov[u] = (short)f2bf(o[f][c4][u] * inv);
      *(bf16x4*)(&merged[base + c4 * 16 + g * 4]) = ov;
    }
  }
}

extern "C" void kernel_launch(void* const* d_in, const int* in_sizes, int n_in,
                              void* d_out, int out_size, void* d_ws, size_t ws_size,
                              hipStream_t stream) {
  const float* x  = (const float*)d_in[0];
  const float* Wq = (const float*)d_in[1];
  const float* bq = (const float*)d_in[2];
  const float* Wk = (const float*)d_in[3];
  const float* bk = (const float*)d_in[4];
  const float* Wv = (const float*)d_in[5];
  const float* bv = (const float*)d_in[6];
  const float* Wo = (const float*)d_in[7];
  const float* bo = (const float*)d_in[8];

  if (ws_size < (size_t)42479616) return;

  unsigned short* ws  = (unsigned short*)d_ws;
  unsigned short* qkv  = ws;                       // Q|K [32][2048][64]; Vt [32][64][2048]
  unsigned short* Wob  = ws + 12582912;            // Wo bf16 [1024][1024]
  float* biasQ = (float*)(ws + 13631488);          // fused qkv bias [3072]
  unsigned short* xb = ws + 13899776;              // x bf16 [4096][1024] (dead after gemm0)
  unsigned short* Wb = ws + 18094080;              // Wq'|Wk|Wv bf16 (dead after gemm0)
  unsigned short* mrg = ws + 13899776;             // merged bf16 (overlays dead xb)

  k_prep<<<dim3(8204), dim3(256), 0, stream>>>(x, Wq, Wk, Wv, Wo, bq, bk, bv,
                                               xb, Wb, Wob, biasQ);
  k_gemm0<<<dim3(32, 24), dim3(256), 0, stream>>>(xb, Wb, biasQ, qkv);
  k_attn<<<dim3(512), dim3(256), 0, stream>>>(
      qkv, qkv + 4194304, qkv + 8388608, mrg);
  k_gemm1<<<dim3(32, 8), dim3(512), 0, stream>>>(mrg, Wob, bo, (float*)d_out);
}